// Round 18
// baseline (281.142 us; speedup 1.0000x reference)
//
#include <hip/hip_runtime.h>

#define N_NODES 50000
#define N_EDGES 800000
#define HEADS   8
#define HID     32
#define HC      256
#define NG      64
#define GEMM_TILES (N_NODES / 16)             // 3125 tiles (16 nodes each)
#define NBUCK   196                           // dst >> 8
#define NSUB    4                             // sub-counters per bucket
#define SUBCAP  1280                          // per-sub-region capacity (lambda=1020, +8sigma)
#define EBUF_CAP (NSUB * SUBCAP)              // 5120 per bucket (compact)
#define BUCKA_BLOCKS 196                      // 4096 edges/block
#define POOL_SLICES 16                        // pool stage-1 parallelism per graph
#define GATY_TILES_A 1563                     // gat_y visibility split
#define GATY_TILES_B (GEMM_TILES - GATY_TILES_A)

typedef unsigned short ushort_t;
typedef unsigned int   uint_t;
typedef __attribute__((ext_vector_type(8))) short short8;
typedef __attribute__((ext_vector_type(4))) float f32x4;

// ---- workspace layout (float offsets) ----
#define HB_OFF    0                // hb bf16 N*256 node-major 512B rows (25.6MB)
#define Z_OFF     0                // z fp32 N*32 (alias: born in k_gin_mlp, hb dead)
#define AS_OFF    6400000          // a_s[n][h] fp32 node-major
#define AD_OFF    6800000          // a_d[n][h] fp32 node-major
#define ROW_OFF   7200000          // int row[N+1] (FINAL values)
#define BCNT_OFF  7250016          // int bcnt[196*4*32] each sub-counter on own 128B line [zeroed]
#define GS_OFF    7275200          // int gstart[NG+1]
#define WGBT_OFF  7275296          // bf16 WgT[256][128] (16384 float slots), 16B aligned
#define W1BT_OFF  7291680          // bf16 W1T[32][256] (4096 float slots), 16B aligned
#define CSR_OFF   7295776          // int csr_src[N_EDGES]
#define EBUF_OFF  8095776          // int2 ebuf[196][4][1280] (2007040 ints), 16B aligned
#define Y_OFF     10102816         // y bf16 N*32 (written by k_gat_y epilogue)
#define SUMS_OFF  10902816         // fp32 sums[64][32] [zero-init by k_init]
#define WS_END    10904864

__device__ __forceinline__ ushort_t f2bf(float f) {
    uint_t u = __float_as_uint(f);
    u = (u + 0x7FFFu + ((u >> 16) & 1u)) >> 16;   // RNE
    return (ushort_t)u;
}
__device__ __forceinline__ float bf2f(ushort_t u) { return __uint_as_float((uint_t)u << 16); }
__device__ __forceinline__ float bf_lo(uint_t u) { return __uint_as_float(u << 16); }
__device__ __forceinline__ float bf_hi(uint_t u) { return __uint_as_float(u & 0xFFFF0000u); }

// merged init: bf16 W_gat^T (32768) + zero bcnt (6272 f4) + zero sums (512 f4)
// + bf16 W1^T (8192)
__global__ __launch_bounds__(256) void k_init(const float* __restrict__ Wg,
                                              const float* __restrict__ W1,
                                              ushort_t* __restrict__ wgbT,
                                              ushort_t* __restrict__ w1bT,
                                              float* __restrict__ bcntf,
                                              float* __restrict__ sums) {
    int id = blockIdx.x * 256 + threadIdx.x;
    if (id < 32768) {
        wgbT[(id & 255) * 128 + (id >> 8)] = f2bf(Wg[id]);
    } else if (id < 32768 + 6272) {
        ((float4*)bcntf)[id - 32768] = make_float4(0.f, 0.f, 0.f, 0.f);
    } else if (id < 32768 + 6272 + 512) {
        ((float4*)sums)[id - 32768 - 6272] = make_float4(0.f, 0.f, 0.f, 0.f);
    } else if (id < 32768 + 6272 + 512 + 8192) {
        int j = id - 32768 - 6272 - 512;             // j = k*32 + n
        w1bT[(j & 31) * 256 + (j >> 5)] = f2bf(W1[j]);
    }
}

// ---------- bucket-A edge partition (SPLIT OUT for counter visibility) ----------
__global__ __launch_bounds__(256) void k_bucketA(const int* __restrict__ ei,
                                                 int* __restrict__ bcnt,
                                                 int* __restrict__ ebuf) {
    __shared__ int h[NBUCK];
    __shared__ int base[NBUCK];
    int kb = blockIdx.x;
    int s  = kb & (NSUB - 1);
    int t = threadIdx.x;
    if (t < NBUCK) h[t] = 0;
    __syncthreads();
    int pack[16];
#pragma unroll
    for (int i = 0; i < 16; ++i) {
        int e = kb * 4096 + i * 256 + t;
        pack[i] = -1;
        if (e < N_EDGES) {
            int b = ei[N_EDGES + e] >> 8;
            int lp = atomicAdd(&h[b], 1);
            pack[i] = (b << 16) | lp;       // lp < 4096 fits 16 bits
        }
    }
    __syncthreads();
    if (t < NBUCK && h[t] > 0)
        base[t] = atomicAdd(&bcnt[(t * NSUB + s) * 32], h[t]);
    __syncthreads();
    int2* eb = (int2*)ebuf;
#pragma unroll
    for (int i = 0; i < 16; ++i) {
        if (pack[i] >= 0) {
            int e = kb * 4096 + i * 256 + t;
            int b = pack[i] >> 16, lp = pack[i] & 0xFFFF;
            int pos = base[b] + lp;
            if (pos < SUBCAP)               // Poisson tail guard (P~1e-12)
                eb[(size_t)b * EBUF_CAP + s * SUBCAP + pos] =
                    make_int2(ei[e], ei[N_EDGES + e]);
        }
    }
}

// ---------- MFMA GEMM (SPLIT OUT for counter visibility) ----------
__global__ __launch_bounds__(256) void k_gemm(const float* __restrict__ x,
                                              const ushort_t* __restrict__ wgbT,
                                              const float* __restrict__ att_s,
                                              const float* __restrict__ att_d,
                                              ushort_t* __restrict__ hb,
                                              float* __restrict__ a_s,
                                              float* __restrict__ a_d,
                                              const int* __restrict__ batch,
                                              int* __restrict__ gs) {
    int tile = blockIdx.x;
    int w = threadIdx.x >> 6;
    int colbase = w * 64;
    int lane = threadIdx.x & 63;
    int n0 = tile * 16;
    int col = lane & 15, quad = lane >> 4;

    f32x4 acc[4];
#pragma unroll
    for (int i = 0; i < 4; ++i) acc[i] = (f32x4){0.f, 0.f, 0.f, 0.f};

    const float* xr = x + (size_t)(n0 + col) * 128 + quad * 8;
    const ushort_t* wbase = wgbT + (size_t)(colbase + col) * 128 + quad * 8;
#pragma unroll
    for (int kk = 0; kk < 4; ++kk) {
        float4 xa = *(const float4*)(xr + kk * 32);
        float4 xb = *(const float4*)(xr + kk * 32 + 4);
        short8 af;   // B-operand: x^T[k][node]
        af[0] = (short)f2bf(xa.x); af[1] = (short)f2bf(xa.y);
        af[2] = (short)f2bf(xa.z); af[3] = (short)f2bf(xa.w);
        af[4] = (short)f2bf(xb.x); af[5] = (short)f2bf(xb.y);
        af[6] = (short)f2bf(xb.z); af[7] = (short)f2bf(xb.w);
#pragma unroll
        for (int nt = 0; nt < 4; ++nt) {
            short8 wf = *(const short8*)(wbase + nt * 16 * 128 + kk * 32); // A[ch][k]
            acc[nt] = __builtin_amdgcn_mfma_f32_16x16x32_bf16(wf, af, acc[nt], 0, 0, 0);
        }
    }

    // hb store: lane owns node n0+col; regs hold ch = colbase+nt*16+quad*4+r
    int node = n0 + col;
    ushort_t* hrow = hb + (size_t)node * 256 + colbase + quad * 4;
#pragma unroll
    for (int nt = 0; nt < 4; ++nt) {
        uint2 o;
        o.x = (uint_t)f2bf(acc[nt][0]) | ((uint_t)f2bf(acc[nt][1]) << 16);
        o.y = (uint_t)f2bf(acc[nt][2]) | ((uint_t)f2bf(acc[nt][3]) << 16);
        *(uint2*)(hrow + nt * 16) = o;
    }

    // a_s/a_d: this wave covers 2 heads; lane-local dot, reduce over quads
#pragma unroll
    for (int hl = 0; hl < 2; ++hl) {
        int hg = (colbase >> 5) + hl;
        float4 s0 = *(const float4*)(att_s + colbase + hl * 32 + quad * 4);
        float4 s1 = *(const float4*)(att_s + colbase + hl * 32 + 16 + quad * 4);
        float4 d0 = *(const float4*)(att_d + colbase + hl * 32 + quad * 4);
        float4 d1 = *(const float4*)(att_d + colbase + hl * 32 + 16 + quad * 4);
        f32x4 e = acc[2 * hl], f = acc[2 * hl + 1];
        float ps = e[0]*s0.x + e[1]*s0.y + e[2]*s0.z + e[3]*s0.w
                 + f[0]*s1.x + f[1]*s1.y + f[2]*s1.z + f[3]*s1.w;
        float pd = e[0]*d0.x + e[1]*d0.y + e[2]*d0.z + e[3]*d0.w
                 + f[0]*d1.x + f[1]*d1.y + f[2]*d1.z + f[3]*d1.w;
        ps += __shfl_xor(ps, 16, 64); ps += __shfl_xor(ps, 32, 64);
        pd += __shfl_xor(pd, 16, 64); pd += __shfl_xor(pd, 32, 64);
        if (quad == 0) {
            a_s[(size_t)node * 8 + hg] = ps;
            a_d[(size_t)node * 8 + hg] = pd;
        }
    }

    // gs boundary-detect (node-parallel; batch is sorted)
    int t = threadIdx.x;
    if (t < 16) {
        int n = n0 + t;
        int b0 = batch[n];
        int bp = (n == 0) ? -1 : batch[n - 1];
        for (int g2 = bp + 1; g2 <= b0; ++g2) gs[g2] = n;
        if (n == N_NODES - 1)
            for (int g2 = b0 + 1; g2 <= NG; ++g2) gs[g2] = N_NODES;
    }
}

// bucket-B: per-bucket CSR build in LDS; 1024 threads (196 blocks = <1
// block/CU, so intra-block width is the only parallelism lever).
__global__ __launch_bounds__(1024) void k_bucketB(const int* __restrict__ ebuf,
                                                  const int* __restrict__ bcnt,
                                                  int* __restrict__ row,
                                                  int* __restrict__ csr) {
    __shared__ int h[256], sc[256], cur[256], subc[NSUB];
    int k = blockIdx.x, t = threadIdx.x;
    // inline exclusive scan over the 196 bucket totals -> this block's base
    if (t < 256) {
        int v2 = 0;
        if (t < NBUCK) {
#pragma unroll
            for (int s = 0; s < NSUB; ++s) v2 += bcnt[(t * NSUB + s) * 32];
        }
        sc[t] = v2;
    } else if (t - 256 < NSUB) {
        subc[t - 256] = bcnt[(k * NSUB + (t - 256)) * 32];
    }
    __syncthreads();
    for (int off = 1; off < 256; off <<= 1) {
        int u = 0;
        if (t < 256 && t >= off) u = sc[t - off];
        __syncthreads();
        if (t < 256) sc[t] += u;
        __syncthreads();
    }
    int base = (k == 0) ? 0 : sc[k - 1];     // inclusive[k-1] = exclusive[k]
    __syncthreads();
    if (t < 256) { h[t] = 0; cur[t] = 0; }
    __syncthreads();
    const int2* eb = (const int2*)ebuf + (size_t)k * EBUF_CAP;
    for (int idx = t; idx < EBUF_CAP; idx += 1024) {
        int s = idx / SUBCAP;
        if (idx - s * SUBCAP < subc[s])
            atomicAdd(&h[eb[idx].y & 255], 1);
    }
    __syncthreads();
    int v = (t < 256) ? h[t] : 0;
    if (t < 256) sc[t] = v;
    __syncthreads();
    for (int off = 1; off < 256; off <<= 1) {
        int u = 0;
        if (t < 256 && t >= off) u = sc[t - off];
        __syncthreads();
        if (t < 256) sc[t] += u;
        __syncthreads();
    }
    int lrow = 0;
    if (t < 256) {
        lrow = sc[t] - v;                      // exclusive prefix within bucket
        int n = k * 256 + t;
        if (n < N_NODES) row[n] = base + lrow;
    }
    if (k == 0 && t == 0) row[N_NODES] = N_EDGES;
    __syncthreads();
    if (t < 256) sc[t] = lrow;                 // republish exclusive for gather
    __syncthreads();
    for (int idx = t; idx < EBUF_CAP; idx += 1024) {
        int s = idx / SUBCAP;
        if (idx - s * SUBCAP < subc[s]) {
            int2 sd = eb[idx];
            int dl = sd.y & 255;
            int p = atomicAdd(&cur[dl], 1);
            csr[base + sc[dl] + p] = sd.x;
        }
    }
}

// ---------- fused GAT + W1 projection (R8/R11 structure; n_base for split) ----------
__global__ __launch_bounds__(256) void k_gat_y(const int* __restrict__ row,
                                               const int* __restrict__ csr,
                                               const float* __restrict__ a_s,
                                               const float* __restrict__ a_d,
                                               const ushort_t* __restrict__ hb,
                                               const float* __restrict__ bg,
                                               const ushort_t* __restrict__ w1bT,
                                               ushort_t* __restrict__ yb,
                                               int n_base) {
    __shared__ ushort_t s_out[16][264];        // 528B stride: conflict-free epilogue reads
    int w = threadIdx.x >> 6;
    int lane = threadIdx.x & 63;
    int n0 = n_base + blockIdx.x * 16;

    int c    = lane & 31;                  // channel group: channels c*8 .. c*8+7
    int half = lane >> 5;                  // edge-parity served by this lane
    int hd   = c >> 2;                     // head = (c*8)/32
    const char* as_hd = (const char*)(a_s + hd);        // +src*32B
    const char* hlane = (const char*)hb + c * 16;       // +src*512B
    float4 b0 = *(const float4*)(bg + c * 8);
    float4 b1 = *(const float4*)(bg + c * 8 + 4);

    for (int i = 0; i < 4; ++i) {
        int n = n0 + w * 4 + i;
        int r0 = row[n], r1 = row[n + 1];
        int deg = r1 - r0;
        float ad2 = a_d[n * 8 + hd];
        const int* cp = csr + r0;

        float acc[8];
        float psum;
        {   // implicit self loop, counted once (half 0 carries it)
            float vs = *(const float*)(as_hd + ((size_t)n << 5)) + ad2;
            vs = vs > 0.f ? vs : 0.2f * vs;
            float evs = __expf(vs);
            float wq = (half == 0) ? evs : 0.f;
            uint4 su = *(const uint4*)(hlane + ((size_t)n << 9));
            acc[0] = wq * bf_lo(su.x); acc[1] = wq * bf_hi(su.x);
            acc[2] = wq * bf_lo(su.y); acc[3] = wq * bf_hi(su.y);
            acc[4] = wq * bf_lo(su.z); acc[5] = wq * bf_hi(su.z);
            acc[6] = wq * bf_lo(su.w); acc[7] = wq * bf_hi(su.w);
            psum = wq;
        }

        int j = half;
        for (; j + 6 < deg; j += 8) {          // 4 edges per half per batch
            int   sx[4];
            float av[4];
            uint4 uu[4];
#pragma unroll
            for (int q = 0; q < 4; ++q) sx[q] = cp[j + 2 * q];
#pragma unroll
            for (int q = 0; q < 4; ++q) av[q] = *(const float*)(as_hd + ((size_t)sx[q] << 5));
#pragma unroll
            for (int q = 0; q < 4; ++q) uu[q] = *(const uint4*)(hlane + ((size_t)sx[q] << 9));
#pragma unroll
            for (int q = 0; q < 4; ++q) {
                float v = av[q] + ad2;
                v = v > 0.f ? v : 0.2f * v;
                float ev = __expf(v);
                psum += ev;
                acc[0] = fmaf(ev, bf_lo(uu[q].x), acc[0]);
                acc[1] = fmaf(ev, bf_hi(uu[q].x), acc[1]);
                acc[2] = fmaf(ev, bf_lo(uu[q].y), acc[2]);
                acc[3] = fmaf(ev, bf_hi(uu[q].y), acc[3]);
                acc[4] = fmaf(ev, bf_lo(uu[q].z), acc[4]);
                acc[5] = fmaf(ev, bf_hi(uu[q].z), acc[5]);
                acc[6] = fmaf(ev, bf_lo(uu[q].w), acc[6]);
                acc[7] = fmaf(ev, bf_hi(uu[q].w), acc[7]);
            }
        }
        for (; j < deg; j += 2) {
            int sj = cp[j];
            float v = *(const float*)(as_hd + ((size_t)sj << 5)) + ad2;
            v = v > 0.f ? v : 0.2f * v;
            float ev = __expf(v);
            psum += ev;
            uint4 u = *(const uint4*)(hlane + ((size_t)sj << 9));
            acc[0] = fmaf(ev, bf_lo(u.x), acc[0]);
            acc[1] = fmaf(ev, bf_hi(u.x), acc[1]);
            acc[2] = fmaf(ev, bf_lo(u.y), acc[2]);
            acc[3] = fmaf(ev, bf_hi(u.y), acc[3]);
            acc[4] = fmaf(ev, bf_lo(u.z), acc[4]);
            acc[5] = fmaf(ev, bf_hi(u.z), acc[5]);
            acc[6] = fmaf(ev, bf_lo(u.w), acc[6]);
            acc[7] = fmaf(ev, bf_hi(u.w), acc[7]);
        }

        // merge the two edge-parities
        psum += __shfl_xor(psum, 32, 64);
#pragma unroll
        for (int k2 = 0; k2 < 8; ++k2) acc[k2] += __shfl_xor(acc[k2], 32, 64);

        float inv = 1.0f / psum;
        float o0 = fmaxf(fmaf(acc[0], inv, b0.x), 0.f);
        float o1 = fmaxf(fmaf(acc[1], inv, b0.y), 0.f);
        float o2 = fmaxf(fmaf(acc[2], inv, b0.z), 0.f);
        float o3 = fmaxf(fmaf(acc[3], inv, b0.w), 0.f);
        float o4 = fmaxf(fmaf(acc[4], inv, b1.x), 0.f);
        float o5 = fmaxf(fmaf(acc[5], inv, b1.y), 0.f);
        float o6 = fmaxf(fmaf(acc[6], inv, b1.z), 0.f);
        float o7 = fmaxf(fmaf(acc[7], inv, b1.w), 0.f);
        uint4 o;
        o.x = (uint_t)f2bf(o0) | ((uint_t)f2bf(o1) << 16);
        o.y = (uint_t)f2bf(o2) | ((uint_t)f2bf(o3) << 16);
        o.z = (uint_t)f2bf(o4) | ((uint_t)f2bf(o5) << 16);
        o.w = (uint_t)f2bf(o6) | ((uint_t)f2bf(o7) << 16);
        if (half == 0)
            *(uint4*)&s_out[w * 4 + i][c * 8] = o;
    }
    __syncthreads();

    // epilogue: y[16x32] = s_out[16x256] @ W1 — wave w<2 computes output
    // cols w*16..w*16+15 (8 MFMAs, conflict-free LDS reads via 264 pad).
    if (w < 2) {
        int col = lane & 15, quad = lane >> 4;
        f32x4 acc = (f32x4){0.f, 0.f, 0.f, 0.f};
        const ushort_t* ar = &s_out[col][quad * 8];
        const ushort_t* bp = w1bT + (w * 16 + col) * 256 + quad * 8;
#pragma unroll
        for (int kk = 0; kk < 8; ++kk) {
            short8 af = *(const short8*)(ar + kk * 32);
            short8 bf0 = *(const short8*)(bp + kk * 32);
            acc = __builtin_amdgcn_mfma_f32_16x16x32_bf16(af, bf0, acc, 0, 0, 0);
        }
        ushort_t* yr = yb + (size_t)(n0 + quad * 4) * 32 + w * 16 + col;
#pragma unroll
        for (int r = 0; r < 4; ++r)
            yr[r * 32] = f2bf(acc[r]);
    }
}

// ---------- GIN on bf16 y (64 B rows, L2-resident) + MLP layer 2 ----------
__global__ __launch_bounds__(256) void k_gin_mlp(const int* __restrict__ row,
                                                 const int* __restrict__ csr,
                                                 const ushort_t* __restrict__ yb,
                                                 const float* __restrict__ b1,
                                                 const float* __restrict__ W2,
                                                 const float* __restrict__ b2,
                                                 float* __restrict__ z) {
    __shared__ float s_z[4][32];
    int g = threadIdx.x >> 6;
    int lane = threadIdx.x & 63;
    int n = blockIdx.x * 4 + g;
    int col = lane & 31, half = lane >> 5;
    int r0 = row[n], r1 = row[n + 1];
    const char* ycol = (const char*)(yb + col);     // +sj*64B
    float acc = (half == 0) ? (bf2f(yb[(size_t)n * 32 + col]) + b1[col]) : 0.f;
    int j = r0 + half;                              // this half-wave's edges: stride 2
    for (; j + 14 < r1; j += 16) {                  // 8 gathers in flight
        int ss[8];
#pragma unroll
        for (int i = 0; i < 8; ++i) ss[i] = csr[j + 2 * i];
        float vv[8];
#pragma unroll
        for (int i = 0; i < 8; ++i)
            vv[i] = bf2f(*(const ushort_t*)(ycol + ((size_t)ss[i] << 6)));
        acc += ((vv[0] + vv[1]) + (vv[2] + vv[3])) + ((vv[4] + vv[5]) + (vv[6] + vv[7]));
    }
    for (; j + 6 < r1; j += 8) {
        int s0 = csr[j], s1 = csr[j + 2], s2 = csr[j + 4], s3 = csr[j + 6];
        float v0 = bf2f(*(const ushort_t*)(ycol + ((size_t)s0 << 6)));
        float v1 = bf2f(*(const ushort_t*)(ycol + ((size_t)s1 << 6)));
        float v2 = bf2f(*(const ushort_t*)(ycol + ((size_t)s2 << 6)));
        float v3 = bf2f(*(const ushort_t*)(ycol + ((size_t)s3 << 6)));
        acc += (v0 + v1) + (v2 + v3);
    }
    for (; j < r1; j += 2)
        acc += bf2f(*(const ushort_t*)(ycol + ((size_t)csr[j] << 6)));
    acc += __shfl_xor(acc, 32, 64);
    float z1 = fmaxf(acc, 0.f);
    if (lane < 32) s_z[g][col] = z1;               // wave-private; no barrier
    const float* zr = &s_z[g][0];
    int k0 = half * 16;
    float p = 0.f;
#pragma unroll
    for (int k = 0; k < 16; k += 4) {
        float4 zv = *(const float4*)(zr + k0 + k);
        p = fmaf(zv.x, W2[(k0 + k + 0) * 32 + col], p);
        p = fmaf(zv.y, W2[(k0 + k + 1) * 32 + col], p);
        p = fmaf(zv.z, W2[(k0 + k + 2) * 32 + col], p);
        p = fmaf(zv.w, W2[(k0 + k + 3) * 32 + col], p);
    }
    p += __shfl_xor(p, 32, 64);
    if (lane < 32) z[n * 32 + col] = fmaxf(p + b2[col], 0.f);
}

// ---------- pool stage 1: 64 graphs x 16 slices, LDS-reduce + 32 atomics/block ----------
__global__ __launch_bounds__(256) void k_pool_partial(const float* __restrict__ z,
                                                      const int* __restrict__ gs,
                                                      float* __restrict__ sums) {
    __shared__ float part[8][32];
    int g = blockIdx.x >> 4, s = blockIdx.x & 15;
    int t = threadIdx.x, col = t & 31, q = t >> 5;
    int r0 = gs[g], r1 = gs[g + 1];
    int chunk = (r1 - r0 + POOL_SLICES - 1) / POOL_SLICES;
    int a = r0 + s * chunk;
    int b = min(a + chunk, r1);
    float acc = 0.f;
    for (int r = a + q; r < b; r += 8)
        acc += z[(size_t)r * 32 + col];
    part[q][col] = acc;
    __syncthreads();
    if (t < 32) {
        float v = ((part[0][t] + part[1][t]) + (part[2][t] + part[3][t]))
                + ((part[4][t] + part[5][t]) + (part[6][t] + part[7][t]));
        atomicAdd(&sums[g * 32 + t], v);       // 16 RMWs/address total — negligible
    }
}

// ---------- pool stage 2: mean + final linear (tiny) ----------
__global__ __launch_bounds__(128) void k_pool_out(const float* __restrict__ sums,
                                                  const int* __restrict__ gs,
                                                  const float* __restrict__ Wf,
                                                  const float* __restrict__ bf,
                                                  float* __restrict__ outp) {
    int g = blockIdx.x, t = threadIdx.x;
    float inv = 1.0f / fmaxf((float)(gs[g + 1] - gs[g]), 1.0f);
    float acc = 0.f;
#pragma unroll
    for (int k = 0; k < 32; ++k)
        acc = fmaf(sums[g * 32 + k], Wf[k * 128 + t], acc);
    outp[g * 128 + t] = acc * inv + bf[t];
}

extern "C" void kernel_launch(void* const* d_in, const int* in_sizes, int n_in,
                              void* d_out, int out_size, void* d_ws, size_t ws_size,
                              hipStream_t stream) {
    const float* x     = (const float*)d_in[0];
    const int*   ei    = (const int*)d_in[1];
    const int*   batch = (const int*)d_in[2];
    const float* Wg    = (const float*)d_in[3];
    const float* att_s = (const float*)d_in[4];
    const float* att_d = (const float*)d_in[5];
    const float* bg    = (const float*)d_in[6];
    const float* W1    = (const float*)d_in[7];
    const float* b1    = (const float*)d_in[8];
    const float* W2    = (const float*)d_in[9];
    const float* b2    = (const float*)d_in[10];
    const float* Wf    = (const float*)d_in[11];
    const float* bf    = (const float*)d_in[12];
    float* ws = (float*)d_ws;

    ushort_t* hb   = (ushort_t*)(ws + HB_OFF);
    float* z       = ws + Z_OFF;               // alias into hb (disjoint lifetime)
    float* a_s     = ws + AS_OFF;
    float* a_d     = ws + AD_OFF;
    int*   row     = (int*)(ws + ROW_OFF);
    int*   bcnt    = (int*)(ws + BCNT_OFF);
    int*   gs      = (int*)(ws + GS_OFF);
    ushort_t* wgbT = (ushort_t*)(ws + WGBT_OFF);
    ushort_t* w1bT = (ushort_t*)(ws + W1BT_OFF);
    int*   csr     = (int*)(ws + CSR_OFF);
    int*   ebuf    = (int*)(ws + EBUF_OFF);
    ushort_t* yb   = (ushort_t*)(ws + Y_OFF);
    float* sums    = ws + SUMS_OFF;

    // init: wgbT + zero bcnt + zero sums + w1bT (one launch)
    k_init<<<(32768 + 6272 + 512 + 8192 + 255) / 256, 256, 0, stream>>>(
        Wg, W1, wgbT, w1bT, (float*)bcnt, sums);

    // PROBE: bucketA and GEMM as separate launches (per-kernel counters)
    k_bucketA<<<BUCKA_BLOCKS, 256, 0, stream>>>(ei, bcnt, ebuf);
    k_gemm<<<GEMM_TILES, 256, 0, stream>>>(x, wgbT, att_s, att_d, hb, a_s, a_d, batch, gs);

    // per-bucket CSR build (1024 threads: width is the only parallelism lever)
    k_bucketB<<<NBUCK, 1024, 0, stream>>>(ebuf, bcnt, row, csr);

    // PROBE: gat_y split 2-way (surfaces anything >37.5us on the board)
    k_gat_y<<<GATY_TILES_A, 256, 0, stream>>>(row, csr, a_s, a_d, hb, bg, w1bT, yb, 0);
    k_gat_y<<<GATY_TILES_B, 256, 0, stream>>>(row, csr, a_s, a_d, hb, bg, w1bT, yb,
                                              GATY_TILES_A * 16);

    // GIN on bf16 y + MLP layer 2 -> z (one wave per node, 8-deep gathers)
    k_gin_mlp<<<N_NODES / 4, 256, 0, stream>>>(row, csr, yb, b1, W2, b2, z);

    // per-graph mean pool: parallel partial sums (1024 blocks) + tiny final
    k_pool_partial<<<NG * POOL_SLICES, 256, 0, stream>>>(z, gs, sums);
    k_pool_out<<<NG, 128, 0, stream>>>(sums, gs, Wf, bf, (float*)d_out);
}

// Round 19
// 243.114 us; speedup vs baseline: 1.1564x; 1.1564x over previous
//
#include <hip/hip_runtime.h>

#define N_NODES 50000
#define N_EDGES 800000
#define HEADS   8
#define HID     32
#define HC      256
#define NG      64
#define GEMM_TILES (N_NODES / 16)             // 3125 tiles (16 nodes each)
#define NBUCK   196                           // dst >> 8
#define EBUF_CAP 5120                         // per-bucket capacity (lambda=4096, +16 sigma)
#define BUCKA_BLOCKS 196                      // 4096 edges/block
#define POOL_SLICES 16                        // pool stage-1 parallelism per graph

typedef unsigned short ushort_t;
typedef unsigned int   uint_t;
typedef __attribute__((ext_vector_type(8))) short short8;
typedef __attribute__((ext_vector_type(4))) float f32x4;

// ---- workspace layout (float offsets) ----  [R15 exact]
#define HB_OFF    0                // hb bf16 N*256 node-major 512B rows (25.6MB)
#define Z_OFF     0                // z fp32 N*32 (alias: born in k_gin_mlp, hb dead)
#define AS_OFF    6400000          // a_s[n][h] fp32 node-major
#define AD_OFF    6800000          // a_d[n][h] fp32 node-major
#define ROW_OFF   7200000          // int row[N+1] (FINAL values)
#define BCNT_OFF  7250016          // int bcnt[196*32] padded stride-128B [zero-init by k_init]
#define GS_OFF    7256544          // int gstart[NG+1]
#define WGBT_OFF  7256640          // bf16 WgT[256][128] (16384 float slots)
#define W1BT_OFF  7273024          // bf16 W1T[32][256] (4096 float slots)
#define CSR_OFF   7277120          // int csr_src[N_EDGES]
#define EBUF_OFF  8077120          // int2 ebuf[196][5120] (2007040 ints)
#define Y_OFF     10084160         // y bf16 N*32 (written by k_gat_y epilogue)
#define SUMS_OFF  10884160         // fp32 sums[64][32] [zero-init by k_init]
#define WS_END    10886208

__device__ __forceinline__ ushort_t f2bf(float f) {
    uint_t u = __float_as_uint(f);
    u = (u + 0x7FFFu + ((u >> 16) & 1u)) >> 16;   // RNE
    return (ushort_t)u;
}
__device__ __forceinline__ float bf2f(ushort_t u) { return __uint_as_float((uint_t)u << 16); }
__device__ __forceinline__ float bf_lo(uint_t u) { return __uint_as_float(u << 16); }
__device__ __forceinline__ float bf_hi(uint_t u) { return __uint_as_float(u & 0xFFFF0000u); }

// merged init: bf16 W_gat^T (32768) + zero bcnt (1568 f4) + zero sums (512 f4)
// + bf16 W1^T (8192)
__global__ __launch_bounds__(256) void k_init(const float* __restrict__ Wg,
                                              const float* __restrict__ W1,
                                              ushort_t* __restrict__ wgbT,
                                              ushort_t* __restrict__ w1bT,
                                              float* __restrict__ bcntf,
                                              float* __restrict__ sums) {
    int id = blockIdx.x * 256 + threadIdx.x;
    if (id < 32768) {
        wgbT[(id & 255) * 128 + (id >> 8)] = f2bf(Wg[id]);
    } else if (id < 32768 + 1568) {
        ((float4*)bcntf)[id - 32768] = make_float4(0.f, 0.f, 0.f, 0.f);
    } else if (id < 32768 + 1568 + 512) {
        ((float4*)sums)[id - 32768 - 1568] = make_float4(0.f, 0.f, 0.f, 0.f);
    } else if (id < 32768 + 1568 + 512 + 8192) {
        int j = id - 32768 - 1568 - 512;             // j = k*32 + n
        w1bT[(j & 31) * 256 + (j >> 5)] = f2bf(W1[j]);
    }
}

// ---------- fused: bucket-A edge partition (first)  ||  MFMA GEMM ----------
// R19 delta vs R15: GEMM branch stages the 16x512B x tile in LDS via one
// coalesced cooperative load (256 thr x 32B) instead of each of the 4 waves
// issuing 8 scattered 16B loads over the SAME tile (4x redundant request
// streams — the candidate wall behind R18's isolated k_gemm: 49.6us at
// 2.3% MFMA / 9.5% VALU / 10% HBM). [16][132] pad -> 2-way LDS access (free).
__global__ __launch_bounds__(256) void k_gemm_bucketA(const float* __restrict__ x,
                                                      const ushort_t* __restrict__ wgbT,
                                                      const float* __restrict__ att_s,
                                                      const float* __restrict__ att_d,
                                                      ushort_t* __restrict__ hb,
                                                      float* __restrict__ a_s,
                                                      float* __restrict__ a_d,
                                                      const int* __restrict__ batch,
                                                      int* __restrict__ gs,
                                                      const int* __restrict__ ei,
                                                      int* __restrict__ bcnt,
                                                      int* __restrict__ ebuf) {
    __shared__ float smem[16][132];            // 8448B; bucketA branch reuses as ints
    if (blockIdx.x < BUCKA_BLOCKS) {
        // ---- bucket-A block: partition 4096 edges into dst-buckets ----
        int* h    = (int*)&smem[0][0];         // [NBUCK]
        int* base = h + 256;                   // [NBUCK]
        int kb = blockIdx.x;
        int t = threadIdx.x;
        if (t < NBUCK) h[t] = 0;
        __syncthreads();
        int pack[16];
#pragma unroll
        for (int i = 0; i < 16; ++i) {
            int e = kb * 4096 + i * 256 + t;
            pack[i] = -1;
            if (e < N_EDGES) {
                int b = ei[N_EDGES + e] >> 8;
                int lp = atomicAdd(&h[b], 1);
                pack[i] = (b << 16) | lp;       // lp < 4096 fits 16 bits
            }
        }
        __syncthreads();
        if (t < NBUCK && h[t] > 0) base[t] = atomicAdd(&bcnt[t * 32], h[t]);
        __syncthreads();
        int2* eb = (int2*)ebuf;
#pragma unroll
        for (int i = 0; i < 16; ++i) {
            if (pack[i] >= 0) {
                int e = kb * 4096 + i * 256 + t;
                int b = pack[i] >> 16, lp = pack[i] & 0xFFFF;
                eb[(size_t)b * EBUF_CAP + base[b] + lp] = make_int2(ei[e], ei[N_EDGES + e]);
            }
        }
        return;
    }

    // ---- GEMM tile: 16 nodes x 256 ch, 4 waves each own 64 channels ----
    int tile = blockIdx.x - BUCKA_BLOCKS;
    int t = threadIdx.x;
    int w = t >> 6;
    int colbase = w * 64;
    int lane = t & 63;
    int n0 = tile * 16;
    int col = lane & 15, quad = lane >> 4;

    // stage x tile once, coalesced: thread t loads row t>>4, 32B segment t&15
    {
        int r = t >> 4, cs = t & 15;
        const float* xrow = x + (size_t)(n0 + r) * 128 + cs * 8;
        float4 v0 = *(const float4*)xrow;
        float4 v1 = *(const float4*)(xrow + 4);
        *(float4*)&smem[r][cs * 8]     = v0;
        *(float4*)&smem[r][cs * 8 + 4] = v1;
    }
    __syncthreads();

    f32x4 acc[4];
#pragma unroll
    for (int i = 0; i < 4; ++i) acc[i] = (f32x4){0.f, 0.f, 0.f, 0.f};

    const ushort_t* wbase = wgbT + (size_t)(colbase + col) * 128 + quad * 8;
#pragma unroll
    for (int kk = 0; kk < 4; ++kk) {
        float4 xa = *(const float4*)&smem[col][quad * 8 + kk * 32];
        float4 xb = *(const float4*)&smem[col][quad * 8 + kk * 32 + 4];
        short8 af;   // B-operand: x^T[k][node]
        af[0] = (short)f2bf(xa.x); af[1] = (short)f2bf(xa.y);
        af[2] = (short)f2bf(xa.z); af[3] = (short)f2bf(xa.w);
        af[4] = (short)f2bf(xb.x); af[5] = (short)f2bf(xb.y);
        af[6] = (short)f2bf(xb.z); af[7] = (short)f2bf(xb.w);
#pragma unroll
        for (int nt = 0; nt < 4; ++nt) {
            short8 wf = *(const short8*)(wbase + nt * 16 * 128 + kk * 32); // A[ch][k]
            acc[nt] = __builtin_amdgcn_mfma_f32_16x16x32_bf16(wf, af, acc[nt], 0, 0, 0);
        }
    }

    // hb store: lane owns node n0+col; regs hold ch = colbase+nt*16+quad*4+r
    int node = n0 + col;
    ushort_t* hrow = hb + (size_t)node * 256 + colbase + quad * 4;
#pragma unroll
    for (int nt = 0; nt < 4; ++nt) {
        uint2 o;
        o.x = (uint_t)f2bf(acc[nt][0]) | ((uint_t)f2bf(acc[nt][1]) << 16);
        o.y = (uint_t)f2bf(acc[nt][2]) | ((uint_t)f2bf(acc[nt][3]) << 16);
        *(uint2*)(hrow + nt * 16) = o;
    }

    // a_s/a_d: this wave covers 2 heads; lane-local dot, reduce over quads
#pragma unroll
    for (int hl = 0; hl < 2; ++hl) {
        int hg = (colbase >> 5) + hl;
        float4 s0 = *(const float4*)(att_s + colbase + hl * 32 + quad * 4);
        float4 s1 = *(const float4*)(att_s + colbase + hl * 32 + 16 + quad * 4);
        float4 d0 = *(const float4*)(att_d + colbase + hl * 32 + quad * 4);
        float4 d1 = *(const float4*)(att_d + colbase + hl * 32 + 16 + quad * 4);
        f32x4 e = acc[2 * hl], f = acc[2 * hl + 1];
        float ps = e[0]*s0.x + e[1]*s0.y + e[2]*s0.z + e[3]*s0.w
                 + f[0]*s1.x + f[1]*s1.y + f[2]*s1.z + f[3]*s1.w;
        float pd = e[0]*d0.x + e[1]*d0.y + e[2]*d0.z + e[3]*d0.w
                 + f[0]*d1.x + f[1]*d1.y + f[2]*d1.z + f[3]*d1.w;
        ps += __shfl_xor(ps, 16, 64); ps += __shfl_xor(ps, 32, 64);
        pd += __shfl_xor(pd, 16, 64); pd += __shfl_xor(pd, 32, 64);
        if (quad == 0) {
            a_s[(size_t)node * 8 + hg] = ps;
            a_d[(size_t)node * 8 + hg] = pd;
        }
    }

    // gs boundary-detect (node-parallel; batch is sorted)
    if (t < 16) {
        int n = n0 + t;
        int b0 = batch[n];
        int bp = (n == 0) ? -1 : batch[n - 1];
        for (int g2 = bp + 1; g2 <= b0; ++g2) gs[g2] = n;
        if (n == N_NODES - 1)
            for (int g2 = b0 + 1; g2 <= NG; ++g2) gs[g2] = N_NODES;
    }
}

// bucket-B: per-bucket CSR build entirely in LDS  [R15 exact, 512-thread]
__global__ __launch_bounds__(512) void k_bucketB(const int* __restrict__ ebuf,
                                                 const int* __restrict__ bcnt,
                                                 int* __restrict__ row,
                                                 int* __restrict__ csr) {
    __shared__ int h[256], sc[256], cur[256];
    int k = blockIdx.x, t = threadIdx.x;
    // inline exclusive scan over the 196 bucket counts -> this block's base
    if (t < 256) sc[t] = (t < NBUCK) ? bcnt[t * 32] : 0;
    __syncthreads();
    for (int off = 1; off < 256; off <<= 1) {
        int u = 0;
        if (t < 256 && t >= off) u = sc[t - off];
        __syncthreads();
        if (t < 256) sc[t] += u;
        __syncthreads();
    }
    int base = (k == 0) ? 0 : sc[k - 1];     // inclusive[k-1] = exclusive[k]
    int cnt = bcnt[k * 32];
    __syncthreads();
    if (t < 256) { h[t] = 0; cur[t] = 0; }
    __syncthreads();
    const int2* eb = (const int2*)ebuf + (size_t)k * EBUF_CAP;
    for (int i = t; i < cnt; i += 512) atomicAdd(&h[eb[i].y & 255], 1);
    __syncthreads();
    int v = (t < 256) ? h[t] : 0;
    if (t < 256) sc[t] = v;
    __syncthreads();
    for (int off = 1; off < 256; off <<= 1) {
        int u = 0;
        if (t < 256 && t >= off) u = sc[t - off];
        __syncthreads();
        if (t < 256) sc[t] += u;
        __syncthreads();
    }
    int lrow = 0;
    if (t < 256) {
        lrow = sc[t] - v;                      // exclusive prefix within bucket
        int n = k * 256 + t;
        if (n < N_NODES) row[n] = base + lrow;
    }
    if (k == 0 && t == 0) row[N_NODES] = N_EDGES;
    __syncthreads();
    if (t < 256) sc[t] = lrow;                 // republish exclusive for gather
    __syncthreads();
    for (int i = t; i < cnt; i += 512) {
        int2 sd = eb[i];
        int dl = sd.y & 255;
        int p = atomicAdd(&cur[dl], 1);
        csr[base + sc[dl] + p] = sd.x;
    }
}

// ---------- fused GAT + W1 projection (R8/R11 exact, single launch) ----------
__global__ __launch_bounds__(256) void k_gat_y(const int* __restrict__ row,
                                               const int* __restrict__ csr,
                                               const float* __restrict__ a_s,
                                               const float* __restrict__ a_d,
                                               const ushort_t* __restrict__ hb,
                                               const float* __restrict__ bg,
                                               const ushort_t* __restrict__ w1bT,
                                               ushort_t* __restrict__ yb) {
    __shared__ ushort_t s_out[16][264];        // 528B stride: conflict-free epilogue reads
    int w = threadIdx.x >> 6;
    int lane = threadIdx.x & 63;
    int n0 = blockIdx.x * 16;

    int c    = lane & 31;                  // channel group: channels c*8 .. c*8+7
    int half = lane >> 5;                  // edge-parity served by this lane
    int hd   = c >> 2;                     // head = (c*8)/32
    const char* as_hd = (const char*)(a_s + hd);        // +src*32B
    const char* hlane = (const char*)hb + c * 16;       // +src*512B
    float4 b0 = *(const float4*)(bg + c * 8);
    float4 b1 = *(const float4*)(bg + c * 8 + 4);

    for (int i = 0; i < 4; ++i) {
        int n = n0 + w * 4 + i;
        int r0 = row[n], r1 = row[n + 1];
        int deg = r1 - r0;
        float ad2 = a_d[n * 8 + hd];
        const int* cp = csr + r0;

        float acc[8];
        float psum;
        {   // implicit self loop, counted once (half 0 carries it)
            float vs = *(const float*)(as_hd + ((size_t)n << 5)) + ad2;
            vs = vs > 0.f ? vs : 0.2f * vs;
            float evs = __expf(vs);
            float wq = (half == 0) ? evs : 0.f;
            uint4 su = *(const uint4*)(hlane + ((size_t)n << 9));
            acc[0] = wq * bf_lo(su.x); acc[1] = wq * bf_hi(su.x);
            acc[2] = wq * bf_lo(su.y); acc[3] = wq * bf_hi(su.y);
            acc[4] = wq * bf_lo(su.z); acc[5] = wq * bf_hi(su.z);
            acc[6] = wq * bf_lo(su.w); acc[7] = wq * bf_hi(su.w);
            psum = wq;
        }

        int j = half;
        for (; j + 6 < deg; j += 8) {          // 4 edges per half per batch
            int   sx[4];
            float av[4];
            uint4 uu[4];
#pragma unroll
            for (int q = 0; q < 4; ++q) sx[q] = cp[j + 2 * q];
#pragma unroll
            for (int q = 0; q < 4; ++q) av[q] = *(const float*)(as_hd + ((size_t)sx[q] << 5));
#pragma unroll
            for (int q = 0; q < 4; ++q) uu[q] = *(const uint4*)(hlane + ((size_t)sx[q] << 9));
#pragma unroll
            for (int q = 0; q < 4; ++q) {
                float v = av[q] + ad2;
                v = v > 0.f ? v : 0.2f * v;
                float ev = __expf(v);
                psum += ev;
                acc[0] = fmaf(ev, bf_lo(uu[q].x), acc[0]);
                acc[1] = fmaf(ev, bf_hi(uu[q].x), acc[1]);
                acc[2] = fmaf(ev, bf_lo(uu[q].y), acc[2]);
                acc[3] = fmaf(ev, bf_hi(uu[q].y), acc[3]);
                acc[4] = fmaf(ev, bf_lo(uu[q].z), acc[4]);
                acc[5] = fmaf(ev, bf_hi(uu[q].z), acc[5]);
                acc[6] = fmaf(ev, bf_lo(uu[q].w), acc[6]);
                acc[7] = fmaf(ev, bf_hi(uu[q].w), acc[7]);
            }
        }
        for (; j < deg; j += 2) {
            int sj = cp[j];
            float v = *(const float*)(as_hd + ((size_t)sj << 5)) + ad2;
            v = v > 0.f ? v : 0.2f * v;
            float ev = __expf(v);
            psum += ev;
            uint4 u = *(const uint4*)(hlane + ((size_t)sj << 9));
            acc[0] = fmaf(ev, bf_lo(u.x), acc[0]);
            acc[1] = fmaf(ev, bf_hi(u.x), acc[1]);
            acc[2] = fmaf(ev, bf_lo(u.y), acc[2]);
            acc[3] = fmaf(ev, bf_hi(u.y), acc[3]);
            acc[4] = fmaf(ev, bf_lo(u.z), acc[4]);
            acc[5] = fmaf(ev, bf_hi(u.z), acc[5]);
            acc[6] = fmaf(ev, bf_lo(u.w), acc[6]);
            acc[7] = fmaf(ev, bf_hi(u.w), acc[7]);
        }

        // merge the two edge-parities
        psum += __shfl_xor(psum, 32, 64);
#pragma unroll
        for (int k2 = 0; k2 < 8; ++k2) acc[k2] += __shfl_xor(acc[k2], 32, 64);

        float inv = 1.0f / psum;
        float o0 = fmaxf(fmaf(acc[0], inv, b0.x), 0.f);
        float o1 = fmaxf(fmaf(acc[1], inv, b0.y), 0.f);
        float o2 = fmaxf(fmaf(acc[2], inv, b0.z), 0.f);
        float o3 = fmaxf(fmaf(acc[3], inv, b0.w), 0.f);
        float o4 = fmaxf(fmaf(acc[4], inv, b1.x), 0.f);
        float o5 = fmaxf(fmaf(acc[5], inv, b1.y), 0.f);
        float o6 = fmaxf(fmaf(acc[6], inv, b1.z), 0.f);
        float o7 = fmaxf(fmaf(acc[7], inv, b1.w), 0.f);
        uint4 o;
        o.x = (uint_t)f2bf(o0) | ((uint_t)f2bf(o1) << 16);
        o.y = (uint_t)f2bf(o2) | ((uint_t)f2bf(o3) << 16);
        o.z = (uint_t)f2bf(o4) | ((uint_t)f2bf(o5) << 16);
        o.w = (uint_t)f2bf(o6) | ((uint_t)f2bf(o7) << 16);
        if (half == 0)
            *(uint4*)&s_out[w * 4 + i][c * 8] = o;
    }
    __syncthreads();

    // epilogue: y[16x32] = s_out[16x256] @ W1 — wave w<2 computes output
    // cols w*16..w*16+15 (8 MFMAs, conflict-free LDS reads via 264 pad).
    if (w < 2) {
        int col = lane & 15, quad = lane >> 4;
        f32x4 acc = (f32x4){0.f, 0.f, 0.f, 0.f};
        const ushort_t* ar = &s_out[col][quad * 8];
        const ushort_t* bp = w1bT + (w * 16 + col) * 256 + quad * 8;
#pragma unroll
        for (int kk = 0; kk < 8; ++kk) {
            short8 af = *(const short8*)(ar + kk * 32);
            short8 bf0 = *(const short8*)(bp + kk * 32);
            acc = __builtin_amdgcn_mfma_f32_16x16x32_bf16(af, bf0, acc, 0, 0, 0);
        }
        ushort_t* yr = yb + (size_t)(n0 + quad * 4) * 32 + w * 16 + col;
#pragma unroll
        for (int r = 0; r < 4; ++r)
            yr[r * 32] = f2bf(acc[r]);
    }
}

// ---------- GIN on bf16 y (64 B rows, L2-resident) + MLP layer 2 ----------
__global__ __launch_bounds__(256) void k_gin_mlp(const int* __restrict__ row,
                                                 const int* __restrict__ csr,
                                                 const ushort_t* __restrict__ yb,
                                                 const float* __restrict__ b1,
                                                 const float* __restrict__ W2,
                                                 const float* __restrict__ b2,
                                                 float* __restrict__ z) {
    __shared__ float s_z[4][32];
    int g = threadIdx.x >> 6;
    int lane = threadIdx.x & 63;
    int n = blockIdx.x * 4 + g;
    int col = lane & 31, half = lane >> 5;
    int r0 = row[n], r1 = row[n + 1];
    const char* ycol = (const char*)(yb + col);     // +sj*64B
    float acc = (half == 0) ? (bf2f(yb[(size_t)n * 32 + col]) + b1[col]) : 0.f;
    int j = r0 + half;                              // this half-wave's edges: stride 2
    for (; j + 14 < r1; j += 16) {                  // 8 gathers in flight
        int ss[8];
#pragma unroll
        for (int i = 0; i < 8; ++i) ss[i] = csr[j + 2 * i];
        float vv[8];
#pragma unroll
        for (int i = 0; i < 8; ++i)
            vv[i] = bf2f(*(const ushort_t*)(ycol + ((size_t)ss[i] << 6)));
        acc += ((vv[0] + vv[1]) + (vv[2] + vv[3])) + ((vv[4] + vv[5]) + (vv[6] + vv[7]));
    }
    for (; j + 6 < r1; j += 8) {
        int s0 = csr[j], s1 = csr[j + 2], s2 = csr[j + 4], s3 = csr[j + 6];
        float v0 = bf2f(*(const ushort_t*)(ycol + ((size_t)s0 << 6)));
        float v1 = bf2f(*(const ushort_t*)(ycol + ((size_t)s1 << 6)));
        float v2 = bf2f(*(const ushort_t*)(ycol + ((size_t)s2 << 6)));
        float v3 = bf2f(*(const ushort_t*)(ycol + ((size_t)s3 << 6)));
        acc += (v0 + v1) + (v2 + v3);
    }
    for (; j < r1; j += 2)
        acc += bf2f(*(const ushort_t*)(ycol + ((size_t)csr[j] << 6)));
    acc += __shfl_xor(acc, 32, 64);
    float z1 = fmaxf(acc, 0.f);
    if (lane < 32) s_z[g][col] = z1;               // wave-private; no barrier
    const float* zr = &s_z[g][0];
    int k0 = half * 16;
    float p = 0.f;
#pragma unroll
    for (int k = 0; k < 16; k += 4) {
        float4 zv = *(const float4*)(zr + k0 + k);
        p = fmaf(zv.x, W2[(k0 + k + 0) * 32 + col], p);
        p = fmaf(zv.y, W2[(k0 + k + 1) * 32 + col], p);
        p = fmaf(zv.z, W2[(k0 + k + 2) * 32 + col], p);
        p = fmaf(zv.w, W2[(k0 + k + 3) * 32 + col], p);
    }
    p += __shfl_xor(p, 32, 64);
    if (lane < 32) z[n * 32 + col] = fmaxf(p + b2[col], 0.f);
}

// ---------- pool stage 1: 64 graphs x 16 slices, LDS-reduce + 32 atomics/block ----------
__global__ __launch_bounds__(256) void k_pool_partial(const float* __restrict__ z,
                                                      const int* __restrict__ gs,
                                                      float* __restrict__ sums) {
    __shared__ float part[8][32];
    int g = blockIdx.x >> 4, s = blockIdx.x & 15;
    int t = threadIdx.x, col = t & 31, q = t >> 5;
    int r0 = gs[g], r1 = gs[g + 1];
    int chunk = (r1 - r0 + POOL_SLICES - 1) / POOL_SLICES;
    int a = r0 + s * chunk;
    int b = min(a + chunk, r1);
    float acc = 0.f;
    for (int r = a + q; r < b; r += 8)
        acc += z[(size_t)r * 32 + col];
    part[q][col] = acc;
    __syncthreads();
    if (t < 32) {
        float v = ((part[0][t] + part[1][t]) + (part[2][t] + part[3][t]))
                + ((part[4][t] + part[5][t]) + (part[6][t] + part[7][t]));
        atomicAdd(&sums[g * 32 + t], v);       // 16 RMWs/address total — negligible
    }
}

// ---------- pool stage 2: mean + final linear (tiny) ----------
__global__ __launch_bounds__(128) void k_pool_out(const float* __restrict__ sums,
                                                  const int* __restrict__ gs,
                                                  const float* __restrict__ Wf,
                                                  const float* __restrict__ bf,
                                                  float* __restrict__ outp) {
    int g = blockIdx.x, t = threadIdx.x;
    float inv = 1.0f / fmaxf((float)(gs[g + 1] - gs[g]), 1.0f);
    float acc = 0.f;
#pragma unroll
    for (int k = 0; k < 32; ++k)
        acc = fmaf(sums[g * 32 + k], Wf[k * 128 + t], acc);
    outp[g * 128 + t] = acc * inv + bf[t];
}

extern "C" void kernel_launch(void* const* d_in, const int* in_sizes, int n_in,
                              void* d_out, int out_size, void* d_ws, size_t ws_size,
                              hipStream_t stream) {
    const float* x     = (const float*)d_in[0];
    const int*   ei    = (const int*)d_in[1];
    const int*   batch = (const int*)d_in[2];
    const float* Wg    = (const float*)d_in[3];
    const float* att_s = (const float*)d_in[4];
    const float* att_d = (const float*)d_in[5];
    const float* bg    = (const float*)d_in[6];
    const float* W1    = (const float*)d_in[7];
    const float* b1    = (const float*)d_in[8];
    const float* W2    = (const float*)d_in[9];
    const float* b2    = (const float*)d_in[10];
    const float* Wf    = (const float*)d_in[11];
    const float* bf    = (const float*)d_in[12];
    float* ws = (float*)d_ws;

    ushort_t* hb   = (ushort_t*)(ws + HB_OFF);
    float* z       = ws + Z_OFF;               // alias into hb (disjoint lifetime)
    float* a_s     = ws + AS_OFF;
    float* a_d     = ws + AD_OFF;
    int*   row     = (int*)(ws + ROW_OFF);
    int*   bcnt    = (int*)(ws + BCNT_OFF);
    int*   gs      = (int*)(ws + GS_OFF);
    ushort_t* wgbT = (ushort_t*)(ws + WGBT_OFF);
    ushort_t* w1bT = (ushort_t*)(ws + W1BT_OFF);
    int*   csr     = (int*)(ws + CSR_OFF);
    int*   ebuf    = (int*)(ws + EBUF_OFF);
    ushort_t* yb   = (ushort_t*)(ws + Y_OFF);
    float* sums    = ws + SUMS_OFF;

    // init: wgbT + zero bcnt + zero sums + w1bT (one launch)
    k_init<<<(32768 + 1568 + 512 + 8192 + 255) / 256, 256, 0, stream>>>(
        Wg, W1, wgbT, w1bT, (float*)bcnt, sums);

    // fused: bucket-A partition (first, 196 big blocks) || MFMA projection
    k_gemm_bucketA<<<BUCKA_BLOCKS + GEMM_TILES, 256, 0, stream>>>(
        x, wgbT, att_s, att_d, hb, a_s, a_d, batch, gs, ei, bcnt, ebuf);

    // per-bucket CSR build (inline base-scan + LDS hist/scan/place) -> row, csr
    k_bucketB<<<NBUCK, 512, 0, stream>>>(ebuf, bcnt, row, csr);

    // fused GAT + W1 projection: softmax+gather -> LDS tile -> MFMA -> yb
    k_gat_y<<<GEMM_TILES, 256, 0, stream>>>(row, csr, a_s, a_d, hb, bg, w1bT, yb);

    // GIN on bf16 y + MLP layer 2 -> z (one wave per node, 8-deep gathers)
    k_gin_mlp<<<N_NODES / 4, 256, 0, stream>>>(row, csr, yb, b1, W2, b2, z);

    // per-graph mean pool: parallel partial sums (1024 blocks) + tiny final
    k_pool_partial<<<NG * POOL_SLICES, 256, 0, stream>>>(z, gs, sums);
    k_pool_out<<<NG, 128, 0, stream>>>(sums, gs, Wf, bf, (float*)d_out);
}